// Round 11
// baseline (2550.368 us; speedup 1.0000x reference)
//
#include <hip/hip_runtime.h>
#include <hip/hip_bf16.h>

#define Bb 64
#define Tt 256
#define Ii 256
#define Hh 512
#define Cc 1000

typedef float f4 __attribute__((ext_vector_type(4)));
typedef short s8 __attribute__((ext_vector_type(8)));
typedef unsigned long long u64;

__device__ __forceinline__ unsigned short f2bf(float f) {
  union { float f; unsigned u; } v; v.f = f;
  return (unsigned short)((v.u + 0x7FFFu + ((v.u >> 16) & 1u)) >> 16);
}
__device__ __forceinline__ float sigf(float x) {
  return __builtin_amdgcn_rcpf(1.f + __expf(-x));
}
__device__ __forceinline__ float tanhs(float x) {
  float ax = fabsf(x);
  float e = __expf(-2.f * ax);
  float r = (1.f - e) * __builtin_amdgcn_rcpf(1.f + e);
  return copysignf(r, x);
}

struct PZ {
  const float* x;
  const float* Whh[3]; const float* Wih[3];
  const float* bih[3]; const float* bhh[3];
  const float* fcw;
  float* outbuf;
  unsigned short* y[3];
  unsigned* fl;    // [3][4][64] per-producer flags (t+1), one 64B line each
  unsigned* cnt2;  // [4][256] layer-2 aggregated counters for FC gating
};

__global__ void zero_sync(unsigned* f) {
  int i = blockIdx.x * 256 + threadIdx.x;
  if (i < (3 * 4 * 64 + 4 * 256) * 16) f[i] = 0;
}

__global__ void bias_init_kernel(const float* __restrict__ fcb, float* __restrict__ out) {
  int i = blockIdx.x * 256 + threadIdx.x;
  if (i < Bb * Cc) out[i] = fcb[i % Cc];
}

// grid 256, 1 block/CU. bid<192: LSTM (L=bid>>6, s=bid&63, 8 dims/slice,
// weights in VGPRs, per-wave batch chains). bid>=192: FC (64 blocks, 16 tiles
// each, gated on layer-2 counters so the 524MB fc_w read hides under the scan).
__launch_bounds__(256, 1)
__global__ void mega_kernel(PZ p) {
  const int bid = blockIdx.x;
  const int tid = threadIdx.x;
  const int lane = tid & 63;
  const int w = tid >> 6;
  const int q = lane >> 4;
  const int c = lane & 15;
  const int b = 16 * w + c;

  if (bid < 192) {
    // ======================= LSTM role =======================
    const int L = bid >> 6;
    const int s = bid & 63;
    const int n0 = s * 8;
    const int aswz = (c & 7) << 4;

    __shared__ unsigned short Wst[32 * 512];  // 32 KB staging (Whh then Wih)
    __shared__ __align__(16) unsigned short hstage[4][16][8];

    const int Kin = (L == 0) ? Ii : Hh;

    {  // stage Whh slice (32 gate-rows x 512) swizzled
      const float* src = p.Whh[L];
      for (int idx = tid; idx < 32 * 64; idx += 256) {
        int r = idx >> 6, kk = (idx & 63) << 3;
        int rho = r & 15, tt = r >> 4;
        int j = (rho & 3) * Hh + n0 + 4 * tt + (rho >> 2);
        const float* sr = src + (size_t)j * Hh + kk;
        s8 tv;
#pragma unroll
        for (int e = 0; e < 8; ++e) tv[e] = (short)f2bf(sr[e]);
        int byt = ((r * 512 + kk) * 2) ^ ((r & 7) << 4);
        *(s8*)((char*)Wst + byt) = tv;
      }
    }
    __syncthreads();
    s8 wAr[2][16];  // recurrent A-frags in regs
#pragma unroll
    for (int tt = 0; tt < 2; ++tt)
#pragma unroll
      for (int kc = 0; kc < 16; ++kc)
        wAr[tt][kc] = *(const s8*)((const char*)Wst +
                                   ((((tt * 16 + c) * 512 + kc * 32 + 8 * q) * 2) ^ aswz));
    __syncthreads();
    {  // stage Wih slice
      const float* src = p.Wih[L];
      const int kd8 = Kin >> 3;
      for (int idx = tid; idx < 32 * kd8; idx += 256) {
        int r = idx / kd8, kk = (idx - r * kd8) << 3;
        int rho = r & 15, tt = r >> 4;
        int j = (rho & 3) * Hh + n0 + 4 * tt + (rho >> 2);
        const float* sr = src + (size_t)j * Kin + kk;
        s8 tv;
#pragma unroll
        for (int e = 0; e < 8; ++e) tv[e] = (short)f2bf(sr[e]);
        int byt = ((r * Kin + kk) * 2) ^ ((r & 7) << 4);
        *(s8*)((char*)Wst + byt) = tv;
      }
    }
    __syncthreads();
    s8 wAi[2][16];  // input A-frags in regs
    if (L == 0) {
#pragma unroll
      for (int tt = 0; tt < 2; ++tt)
#pragma unroll
        for (int kc = 0; kc < 8; ++kc)
          wAi[tt][kc] = *(const s8*)((const char*)Wst +
                                     ((((tt * 16 + c) * 256 + kc * 32 + 8 * q) * 2) ^ aswz));
    } else {
#pragma unroll
      for (int tt = 0; tt < 2; ++tt)
#pragma unroll
        for (int kc = 0; kc < 16; ++kc)
          wAi[tt][kc] = *(const s8*)((const char*)Wst +
                                     ((((tt * 16 + c) * 512 + kc * 32 + 8 * q) * 2) ^ aswz));
    }

    f4 bias2[2];
#pragma unroll
    for (int tt = 0; tt < 2; ++tt)
#pragma unroll
      for (int g = 0; g < 4; ++g) {
        int bi = g * Hh + n0 + 4 * tt + q;  // lane (q,c) tile tt -> dim n0+4tt+q
        bias2[tt][g] = p.bih[L][bi] + p.bhh[L][bi];
      }
    float cs0 = 0.f, cs1 = 0.f;

    unsigned short* yl = p.y[L];
    const unsigned short* ylow = (L > 0) ? p.y[L - 1] : (const unsigned short*)0;
    unsigned* flin = (L > 0) ? p.fl + ((L - 1) * 4 + w) * 64 * 16 : (unsigned*)0;
    unsigned* flown = p.fl + (L * 4 + w) * 64 * 16;
    unsigned* myfl = flown + s * 16;

    for (int t = 0; t < Tt; ++t) {
      f4 a0 = bias2[0], a1 = bias2[1];

      // ---- input acquisition + GEMM (before the h wait) ----
      if (L == 0) {
        const float* xr = p.x + ((size_t)b * Tt + t) * Ii + 8 * q;
#pragma unroll
        for (int kc = 0; kc < 8; ++kc) {
          f4 xa = *(const f4*)(xr + kc * 32);
          f4 xc = *(const f4*)(xr + kc * 32 + 4);
          s8 xb;
#pragma unroll
          for (int e = 0; e < 4; ++e) { xb[e] = (short)f2bf(xa[e]); xb[e + 4] = (short)f2bf(xc[e]); }
          a0 = __builtin_amdgcn_mfma_f32_16x16x32_bf16(wAi[0][kc], xb, a0, 0, 0, 0);
          a1 = __builtin_amdgcn_mfma_f32_16x16x32_bf16(wAi[1][kc], xb, a1, 0, 0, 0);
        }
      } else {
        // wave-parallel poll: lane l watches producer block l (64 <-> 64)
        while (!__all(__hip_atomic_load(flin + lane * 16, __ATOMIC_RELAXED,
                                        __HIP_MEMORY_SCOPE_AGENT) >= (unsigned)(t + 1)))
          __builtin_amdgcn_s_sleep(1);
        asm volatile("" ::: "memory");
        const unsigned short* yr = ylow + ((size_t)b * Tt + t) * Hh + 8 * q;
        s8 yb[16];
#pragma unroll
        for (int kc = 0; kc < 16; ++kc) yb[kc] = *(const s8*)(yr + kc * 32);
#pragma unroll
        for (int kc = 0; kc < 16; ++kc) {
          a0 = __builtin_amdgcn_mfma_f32_16x16x32_bf16(wAi[0][kc], yb[kc], a0, 0, 0, 0);
          a1 = __builtin_amdgcn_mfma_f32_16x16x32_bf16(wAi[1][kc], yb[kc], a1, 0, 0, 0);
        }
      }

      // ---- h[t-1] ----
      if (t > 0) {
        while (!__all(__hip_atomic_load(flown + lane * 16, __ATOMIC_RELAXED,
                                        __HIP_MEMORY_SCOPE_AGENT) >= (unsigned)t))
          __builtin_amdgcn_s_sleep(1);
        asm volatile("" ::: "memory");
        const unsigned short* hr = yl + ((size_t)b * Tt + (t - 1)) * Hh + 8 * q;
        s8 hb[16];
#pragma unroll
        for (int kc = 0; kc < 16; ++kc) hb[kc] = *(const s8*)(hr + kc * 32);
#pragma unroll
        for (int kc = 0; kc < 16; ++kc) {
          a0 = __builtin_amdgcn_mfma_f32_16x16x32_bf16(wAr[0][kc], hb[kc], a0, 0, 0, 0);
          a1 = __builtin_amdgcn_mfma_f32_16x16x32_bf16(wAr[1][kc], hb[kc], a1, 0, 0, 0);
        }
      }

      // ---- pointwise: tile tt -> dim n0+4tt+q, gates {i,f,g,o} = acc[0..3] ----
      {
        float i0 = sigf(a0[0]), f0 = sigf(a0[1]), g0 = tanhs(a0[2]), o0 = sigf(a0[3]);
        cs0 = f0 * cs0 + i0 * g0;
        hstage[w][c][q] = f2bf(o0 * tanhs(cs0));
        float i1 = sigf(a1[0]), f1 = sigf(a1[1]), g1 = tanhs(a1[2]), o1 = sigf(a1[3]);
        cs1 = f1 * cs1 + i1 * g1;
        hstage[w][c][4 + q] = f2bf(o1 * tanhs(cs1));
      }
      asm volatile("s_waitcnt lgkmcnt(0)" ::: "memory");
      __builtin_amdgcn_sched_barrier(0);
      if (lane < 32) {  // repack: batch=lane&15, half=lane>>4 -> one u64 each
        int bb = lane & 15, hf = lane >> 4;
        u64 hv = *(const u64*)&hstage[w][bb][4 * hf];
        u64* dst = (u64*)(yl + ((size_t)(16 * w + bb) * Tt + t) * Hh + n0 + 4 * hf);
        __hip_atomic_store(dst, hv, __ATOMIC_RELAXED, __HIP_MEMORY_SCOPE_AGENT);
      }
      asm volatile("s_waitcnt vmcnt(0)" ::: "memory");  // h acked at LLC
      if (lane == 0) {
        __hip_atomic_store(myfl, (unsigned)(t + 1), __ATOMIC_RELAXED, __HIP_MEMORY_SCOPE_AGENT);
        if (L == 2) atomicAdd(p.cnt2 + (w * 256 + t) * 16, 1u);  // FC gate, no wait
      }
    }
  } else {
    // ======================= FC role =======================
    const int fcid = bid - 192;
    const int KT = Tt * Hh;
    const unsigned short* y2 = p.y[2];
    for (int ti = fcid; ti < 1024; ti += 64) {
      const int kch = ti >> 5, ct = ti & 31;
      const int tneed = kch * 8 + 7;
      bool ok;
      do {  // all 4 per-wave layer-2 chains past tneed (64 producers each)
        unsigned v = 64u;
        if (lane < 4)
          v = __hip_atomic_load(p.cnt2 + (lane * 256 + tneed) * 16, __ATOMIC_RELAXED,
                                __HIP_MEMORY_SCOPE_AGENT);
        ok = __all(v >= 64u);
        if (!ok) __builtin_amdgcn_s_sleep(8);
      } while (!ok);
      asm volatile("" ::: "memory");

      const int kbase = kch * 4096 + q * 8;
      const int c0 = ct * 32 + c;
      const int c1 = c0 + 16;
      const bool v0 = (c0 < Cc), v1 = (c1 < Cc);
      const float* w0 = p.fcw + (size_t)c0 * KT;
      const float* w1 = p.fcw + (size_t)c1 * KT;
      const unsigned short* yr = y2 + (size_t)b * KT;
      f4 a0 = {0.f, 0.f, 0.f, 0.f}, a1 = {0.f, 0.f, 0.f, 0.f};
      for (int kk = 0; kk < 4096; kk += 32) {
        const int k = kbase + kk;
        s8 bf = *(const s8*)(yr + k);
        s8 wa0 = {0, 0, 0, 0, 0, 0, 0, 0}, wa1 = {0, 0, 0, 0, 0, 0, 0, 0};
        if (v0) {
#pragma unroll
          for (int qq = 0; qq < 8; ++qq) wa0[qq] = (short)f2bf(w0[k + qq]);
        }
        if (v1) {
#pragma unroll
          for (int qq = 0; qq < 8; ++qq) wa1[qq] = (short)f2bf(w1[k + qq]);
        }
        a0 = __builtin_amdgcn_mfma_f32_16x16x32_bf16(wa0, bf, a0, 0, 0, 0);
        a1 = __builtin_amdgcn_mfma_f32_16x16x32_bf16(wa1, bf, a1, 0, 0, 0);
      }
      const int rr = q * 4;
#pragma unroll
      for (int qq = 0; qq < 4; ++qq) {
        int ca = ct * 32 + rr + qq;
        if (ca < Cc) atomicAdd(p.outbuf + (size_t)b * Cc + ca, a0[qq]);
        int cb2 = ca + 16;
        if (cb2 < Cc) atomicAdd(p.outbuf + (size_t)b * Cc + cb2, a1[qq]);
      }
    }
  }
}

extern "C" void kernel_launch(void* const* d_in, const int* in_sizes, int n_in,
                              void* d_out, int out_size, void* d_ws, size_t ws_size,
                              hipStream_t stream) {
  PZ p;
  p.x = (const float*)d_in[0];
  p.Wih[0] = (const float*)d_in[1];  p.Whh[0] = (const float*)d_in[2];
  p.bih[0] = (const float*)d_in[3];  p.bhh[0] = (const float*)d_in[4];
  p.Wih[1] = (const float*)d_in[5];  p.Whh[1] = (const float*)d_in[6];
  p.bih[1] = (const float*)d_in[7];  p.bhh[1] = (const float*)d_in[8];
  p.Wih[2] = (const float*)d_in[9];  p.Whh[2] = (const float*)d_in[10];
  p.bih[2] = (const float*)d_in[11]; p.bhh[2] = (const float*)d_in[12];
  p.fcw = (const float*)d_in[13];
  const float* fcb = (const float*)d_in[14];
  p.outbuf = (float*)d_out;

  char* ws = (char*)d_ws;
  p.fl = (unsigned*)ws;                  // 3*4*64 flags x 64B = 48 KB
  p.cnt2 = p.fl + 3 * 4 * 64 * 16;       // 4*256 counters x 64B = 64 KB
  const size_t ysz = (size_t)Bb * Tt * Hh;
  unsigned short* y0 = (unsigned short*)(ws + 114688);
  p.y[0] = y0;
  p.y[1] = y0 + ysz;
  p.y[2] = y0 + 2 * ysz;

  zero_sync<<<112, 256, 0, stream>>>(p.fl);
  bias_init_kernel<<<250, 256, 0, stream>>>(fcb, (float*)d_out);
  mega_kernel<<<256, 256, 0, stream>>>(p);
}

// Round 13
// 1755.177 us; speedup vs baseline: 1.4531x; 1.4531x over previous
//
#include <hip/hip_runtime.h>
#include <hip/hip_bf16.h>

#define Bb 64
#define Tt 256
#define Ii 256
#define Hh 512
#define Cc 1000
#define SENT 0x7F80u  // bf16 +inf; |h|<1 so never produced

typedef float f4 __attribute__((ext_vector_type(4)));
typedef short s8 __attribute__((ext_vector_type(8)));
typedef unsigned long long u64;

__device__ __forceinline__ unsigned short f2bf(float f) {
  union { float f; unsigned u; } v; v.f = f;
  return (unsigned short)((v.u + 0x7FFFu + ((v.u >> 16) & 1u)) >> 16);
}
__device__ __forceinline__ float sigf(float x) {
  return __builtin_amdgcn_rcpf(1.f + __expf(-x));
}
__device__ __forceinline__ float tanhs(float x) {
  float ax = fabsf(x);
  float e = __expf(-2.f * ax);
  float r = (1.f - e) * __builtin_amdgcn_rcpf(1.f + e);
  return copysignf(r, x);
}

// LLC load (bypass L1+L2): proven in R8. Needed so sentinel re-reads never hit
// a stale local-L2 copy.
__device__ __forceinline__ s8 ld128_llc(const unsigned short* p) {
  s8 v;
  asm volatile("global_load_dwordx4 %0, %1, off sc0 sc1" : "=&v"(v) : "v"(p) : "memory");
  return v;
}
#define VMCNT0 asm volatile("s_waitcnt vmcnt(0)" ::: "memory")
#define SBAR __builtin_amdgcn_sched_barrier(0)

__device__ __forceinline__ bool chk(s8 v) {  // both 8B halves non-sentinel
  return ((unsigned short)v[0] != (unsigned short)SENT) &
         ((unsigned short)v[4] != (unsigned short)SENT);
}

struct PT {
  const float* x;
  const float* Whh[3]; const float* Wih[3];
  const float* bih[3]; const float* bhh[3];
  const float* fcw;
  float* outbuf;
  unsigned short* y[3];
  unsigned* fl;    // [(L*32+s)*4+w]*16 per-producer flags (t+1), fire-and-forget
  unsigned* fcfl;  // [(s*4+w)]*16 layer-2 drained flags (every 8th step)
};

__global__ void zero_sync(unsigned* f) {
  int i = blockIdx.x * 256 + threadIdx.x;
  if (i < 8192) f[i] = 0;
}

// sentinel pre-fill of all y buffers (agent scope -> LLC)
__global__ void fill_y(u64* p) {
  const u64 pat = 0x7F807F807F807F80ull;
  size_t g = (size_t)blockIdx.x * 256 + threadIdx.x;
#pragma unroll
  for (int i = 0; i < 16; ++i)
    __hip_atomic_store(p + g + (size_t)i * 393216, pat, __ATOMIC_RELAXED,
                       __HIP_MEMORY_SCOPE_AGENT);
}

__global__ void bias_init_kernel(const float* __restrict__ fcb, float* __restrict__ out) {
  int i = blockIdx.x * 256 + threadIdx.x;
  if (i < Bb * Cc) out[i] = fcb[i % Cc];
}

// grid 256, 1 block/CU. bid<96: LSTM (L=bid>>5, s=bid&31, 16 dims/slice, per-wave
// batch chains). bid>=96: FC (160 blocks, tiles gated on fcfl).
// Sync: producers fire-and-forget (h stores + flag, NO drain). Consumers: poll
// flags -> one LLC payload read -> sentinel verify -> selective re-read (rare).
__launch_bounds__(256, 1)
__global__ void mega_kernel(PT p) {
  const int bid = blockIdx.x;
  const int tid = threadIdx.x;
  const int lane = tid & 63;
  const int w = tid >> 6;
  const int q = lane >> 4;
  const int c = lane & 15;
  const int b = 16 * w + c;

  __shared__ unsigned short Whl[64 * 512];  // 64 KB swizzled (recurrent)
  __shared__ unsigned short Wil[64 * 512];  // 64 KB (input; L0 uses 64x256)

  if (bid < 96) {
    const int L = bid >> 5;
    const int s = bid & 31;
    const int n0 = s * 16;

    const int Kin = (L == 0) ? Ii : Hh;
    {  // stage: LDS row r=tt*16+rho <- gate-row (rho&3)*H + n0 + 4*(rho>>2) + tt
      const float* src = p.Whh[L];
      for (int idx = tid; idx < 64 * 64; idx += 256) {
        int r = idx >> 6, kk = (idx & 63) << 3;
        int rho = r & 15, tt = r >> 4;
        int j = (rho & 3) * Hh + n0 + 4 * (rho >> 2) + tt;
        const float* sr = src + (size_t)j * Hh + kk;
        s8 tv;
#pragma unroll
        for (int e = 0; e < 8; ++e) tv[e] = (short)f2bf(sr[e]);
        int byt = ((r * 512 + kk) * 2) ^ ((r & 7) << 4);
        *(s8*)((char*)Whl + byt) = tv;
      }
      const float* si = p.Wih[L];
      const int kd8 = Kin >> 3;
      for (int idx = tid; idx < 64 * kd8; idx += 256) {
        int r = idx / kd8, kk = (idx - r * kd8) << 3;
        int rho = r & 15, tt = r >> 4;
        int j = (rho & 3) * Hh + n0 + 4 * (rho >> 2) + tt;
        const float* sr = si + (size_t)j * Kin + kk;
        s8 tv;
#pragma unroll
        for (int e = 0; e < 8; ++e) tv[e] = (short)f2bf(sr[e]);
        int byt = ((r * Kin + kk) * 2) ^ ((r & 7) << 4);
        *(s8*)((char*)Wil + byt) = tv;
      }
    }

    f4 bias[4];
#pragma unroll
    for (int tt = 0; tt < 4; ++tt)
#pragma unroll
      for (int g = 0; g < 4; ++g) {
        int bi = g * Hh + n0 + 4 * q + tt;  // lane (q,c) tile tt -> dim n0+4q+tt
        bias[tt][g] = p.bih[L][bi] + p.bhh[L][bi];
      }
    float cst[4] = {0.f, 0.f, 0.f, 0.f};
    __syncthreads();

    const int aswz = (c & 7) << 4;
    unsigned short* yl = p.y[L];
    const unsigned short* ylow = (L > 0) ? p.y[L - 1] : (const unsigned short*)0;
    unsigned* flin = (L > 0) ? p.fl + ((L - 1) * 32) * 4 * 16 : (unsigned*)0;
    unsigned* myfl = p.fl + ((L * 32 + s) * 4 + w) * 16;

    for (int t = 0; t < Tt; ++t) {
      f4 acc[4];
#pragma unroll
      for (int tt = 0; tt < 4; ++tt) acc[tt] = bias[tt];

      // ---- input acquisition + GEMM ----
      if (L == 0) {
        const float* xr = p.x + ((size_t)b * Tt + t) * Ii + 8 * q;
#pragma unroll
        for (int kc = 0; kc < 8; ++kc) {
          f4 xa = *(const f4*)(xr + kc * 32);
          f4 xc = *(const f4*)(xr + kc * 32 + 4);
          s8 xb;
#pragma unroll
          for (int e = 0; e < 4; ++e) { xb[e] = (short)f2bf(xa[e]); xb[e + 4] = (short)f2bf(xc[e]); }
#pragma unroll
          for (int tt = 0; tt < 4; ++tt) {
            int byt = (((tt * 16 + c) * 256 + kc * 32 + 8 * q) * 2) ^ aswz;
            s8 wa = *(const s8*)((const char*)Wil + byt);
            acc[tt] = __builtin_amdgcn_mfma_f32_16x16x32_bf16(wa, xb, acc[tt], 0, 0, 0);
          }
        }
      } else {
        // poll 32 producer flags of layer L-1 (this wave index)
        while (!__all(lane < 32
                          ? __hip_atomic_load(flin + (lane * 4 + w) * 16, __ATOMIC_RELAXED,
                                              __HIP_MEMORY_SCOPE_AGENT) >= (unsigned)(t + 1)
                          : true))
          __builtin_amdgcn_s_sleep(1);
        asm volatile("" ::: "memory");
        const unsigned short* yr = ylow + ((size_t)b * Tt + t) * Hh + 8 * q;
        s8 yb[16];
#pragma unroll
        for (int kc = 0; kc < 16; ++kc) yb[kc] = ld128_llc(yr + kc * 32);
        VMCNT0; SBAR;
        while (1) {  // sentinel verify + selective re-read (insurance, rare)
          unsigned bad = 0;
#pragma unroll
          for (int kc = 0; kc < 16; ++kc)
            if (!chk(yb[kc])) bad |= (1u << kc);
          if (__all(bad == 0)) break;
          __builtin_amdgcn_s_sleep(1);
#pragma unroll
          for (int kc = 0; kc < 16; ++kc)
            if (bad & (1u << kc)) yb[kc] = ld128_llc(yr + kc * 32);
          VMCNT0; SBAR;
        }
#pragma unroll
        for (int tt = 0; tt < 4; ++tt)
#pragma unroll
          for (int kc = 0; kc < 16; ++kc) {
            int byt = (((tt * 16 + c) * 512 + kc * 32 + 8 * q) * 2) ^ aswz;
            s8 wa = *(const s8*)((const char*)Wil + byt);
            acc[tt] = __builtin_amdgcn_mfma_f32_16x16x32_bf16(wa, yb[kc], acc[tt], 0, 0, 0);
          }
      }

      // ---- h[t-1] ----
      if (t > 0) {
        unsigned* flown = p.fl + (L * 32) * 4 * 16;
        while (!__all(lane < 32
                          ? __hip_atomic_load(flown + (lane * 4 + w) * 16, __ATOMIC_RELAXED,
                                              __HIP_MEMORY_SCOPE_AGENT) >= (unsigned)t
                          : true))
          __builtin_amdgcn_s_sleep(1);
        asm volatile("" ::: "memory");
        const unsigned short* hr = yl + ((size_t)b * Tt + (t - 1)) * Hh + 8 * q;
        s8 hb[16];
#pragma unroll
        for (int kc = 0; kc < 16; ++kc) hb[kc] = ld128_llc(hr + kc * 32);
        VMCNT0; SBAR;
        while (1) {
          unsigned bad = 0;
#pragma unroll
          for (int kc = 0; kc < 16; ++kc)
            if (!chk(hb[kc])) bad |= (1u << kc);
          if (__all(bad == 0)) break;
          __builtin_amdgcn_s_sleep(1);
#pragma unroll
          for (int kc = 0; kc < 16; ++kc)
            if (bad & (1u << kc)) hb[kc] = ld128_llc(hr + kc * 32);
          VMCNT0; SBAR;
        }
#pragma unroll
        for (int tt = 0; tt < 4; ++tt)
#pragma unroll
          for (int kc = 0; kc < 16; ++kc) {
            int byt = (((tt * 16 + c) * 512 + kc * 32 + 8 * q) * 2) ^ aswz;
            s8 wa = *(const s8*)((const char*)Whl + byt);
            acc[tt] = __builtin_amdgcn_mfma_f32_16x16x32_bf16(wa, hb[kc], acc[tt], 0, 0, 0);
          }
      }

      // ---- pointwise: lane (q,c) dims n0+4q+tt, gates {i,f,g,o}=acc[tt][0..3] ----
      unsigned short hu[4];
#pragma unroll
      for (int tt = 0; tt < 4; ++tt) {
        float ii = sigf(acc[tt][0]), ff = sigf(acc[tt][1]);
        float gg = tanhs(acc[tt][2]), oo = sigf(acc[tt][3]);
        cst[tt] = ff * cst[tt] + ii * gg;
        hu[tt] = f2bf(oo * tanhs(cst[tt]));
      }
      u64 hv = (u64)hu[0] | ((u64)hu[1] << 16) | ((u64)hu[2] << 32) | ((u64)hu[3] << 48);
      u64* dst = (u64*)(yl + ((size_t)b * Tt + t) * Hh + n0 + 4 * q);
      // fire-and-forget: h store + flag, NO drain (consumers verify sentinels)
      __hip_atomic_store(dst, hv, __ATOMIC_RELAXED, __HIP_MEMORY_SCOPE_AGENT);
      if (lane == 0)
        __hip_atomic_store(myfl, (unsigned)(t + 1), __ATOMIC_RELAXED, __HIP_MEMORY_SCOPE_AGENT);
      // layer-2 only: amortized drained release for FC (sound gate, every 8 steps)
      if (L == 2 && (t & 7) == 7) {
        VMCNT0;
        if (lane == 0)
          __hip_atomic_store(p.fcfl + (s * 4 + w) * 16, (unsigned)(t + 1), __ATOMIC_RELAXED,
                             __HIP_MEMORY_SCOPE_AGENT);
      }
    }
  } else {
    // ======================= FC role =======================
    const int fcid = bid - 96;
    const int KT = Tt * Hh;
    const unsigned short* y2 = p.y[2];
    for (int ti = fcid; ti < 1024; ti += 160) {
      const int kch = ti >> 5, ct = ti & 31;
      const unsigned tneed1 = (unsigned)(kch * 8 + 8);  // fcfl value releasing this k-chunk
      bool ok;
      do {
        unsigned v = 0xFFFFFFFFu;
        if (lane < 32) {
          unsigned mn = 0xFFFFFFFFu;
#pragma unroll
          for (int ww = 0; ww < 4; ++ww) {
            unsigned vv = __hip_atomic_load(p.fcfl + (lane * 4 + ww) * 16, __ATOMIC_RELAXED,
                                            __HIP_MEMORY_SCOPE_AGENT);
            mn = mn < vv ? mn : vv;
          }
          v = mn;
        }
        ok = __all(v >= tneed1);
        if (!ok) __builtin_amdgcn_s_sleep(16);
      } while (!ok);
      asm volatile("" ::: "memory");

      const int kbase = kch * 4096 + q * 8;
      const int c0 = ct * 32 + c;
      const int c1 = c0 + 16;
      const bool v0 = (c0 < Cc), v1 = (c1 < Cc);
      const float* w0 = p.fcw + (size_t)c0 * KT;
      const float* w1 = p.fcw + (size_t)c1 * KT;
      const unsigned short* yr = y2 + (size_t)b * KT;
      f4 a0 = {0.f, 0.f, 0.f, 0.f}, a1 = {0.f, 0.f, 0.f, 0.f};
      for (int kk = 0; kk < 4096; kk += 32) {
        const int k = kbase + kk;
        s8 bf = *(const s8*)(yr + k);
        s8 wa0 = {0, 0, 0, 0, 0, 0, 0, 0}, wa1 = {0, 0, 0, 0, 0, 0, 0, 0};
        if (v0) {
#pragma unroll
          for (int qq = 0; qq < 8; ++qq) wa0[qq] = (short)f2bf(w0[k + qq]);
        }
        if (v1) {
#pragma unroll
          for (int qq = 0; qq < 8; ++qq) wa1[qq] = (short)f2bf(w1[k + qq]);
        }
        a0 = __builtin_amdgcn_mfma_f32_16x16x32_bf16(wa0, bf, a0, 0, 0, 0);
        a1 = __builtin_amdgcn_mfma_f32_16x16x32_bf16(wa1, bf, a1, 0, 0, 0);
      }
      const int rr = q * 4;
#pragma unroll
      for (int qq = 0; qq < 4; ++qq) {
        int ca = ct * 32 + rr + qq;
        if (ca < Cc) atomicAdd(p.outbuf + (size_t)b * Cc + ca, a0[qq]);
        int cb2 = ca + 16;
        if (cb2 < Cc) atomicAdd(p.outbuf + (size_t)b * Cc + cb2, a1[qq]);
      }
    }
  }
}

extern "C" void kernel_launch(void* const* d_in, const int* in_sizes, int n_in,
                              void* d_out, int out_size, void* d_ws, size_t ws_size,
                              hipStream_t stream) {
  PT p;
  p.x = (const float*)d_in[0];
  p.Wih[0] = (const float*)d_in[1];  p.Whh[0] = (const float*)d_in[2];
  p.bih[0] = (const float*)d_in[3];  p.bhh[0] = (const float*)d_in[4];
  p.Wih[1] = (const float*)d_in[5];  p.Whh[1] = (const float*)d_in[6];
  p.bih[1] = (const float*)d_in[7];  p.bhh[1] = (const float*)d_in[8];
  p.Wih[2] = (const float*)d_in[9];  p.Whh[2] = (const float*)d_in[10];
  p.bih[2] = (const float*)d_in[11]; p.bhh[2] = (const float*)d_in[12];
  p.fcw = (const float*)d_in[13];
  const float* fcb = (const float*)d_in[14];
  p.outbuf = (float*)d_out;

  char* ws = (char*)d_ws;
  p.fl = (unsigned*)ws;                 // 24 KB spread flags
  p.fcfl = p.fl + 6144;                 // 8 KB fc gates
  const size_t ysz = (size_t)Bb * Tt * Hh;
  unsigned short* y0 = (unsigned short*)(ws + 65536);
  p.y[0] = y0;
  p.y[1] = y0 + ysz;
  p.y[2] = y0 + 2 * ysz;

  zero_sync<<<32, 256, 0, stream>>>(p.fl);
  fill_y<<<1536, 256, 0, stream>>>((u64*)y0);  // 3*ysz*2 B = 6291456 u64 exactly
  bias_init_kernel<<<250, 256, 0, stream>>>(fcb, (float*)d_out);
  mega_kernel<<<256, 256, 0, stream>>>(p);
}

// Round 15
// 1753.043 us; speedup vs baseline: 1.4548x; 1.0012x over previous
//
#include <hip/hip_runtime.h>
#include <hip/hip_bf16.h>

#define Bb 64
#define Tt 256
#define Ii 256
#define Hh 512
#define Cc 1000
#define SENT 0x7F80u  // bf16 +inf; |h|<1 so never produced

typedef float f4 __attribute__((ext_vector_type(4)));
typedef short s8 __attribute__((ext_vector_type(8)));
typedef unsigned long long u64;

__device__ __forceinline__ unsigned short f2bf(float f) {
  union { float f; unsigned u; } v; v.f = f;
  return (unsigned short)((v.u + 0x7FFFu + ((v.u >> 16) & 1u)) >> 16);
}
__device__ __forceinline__ float sigf(float x) {
  return __builtin_amdgcn_rcpf(1.f + __expf(-x));
}
__device__ __forceinline__ float tanhs(float x) {
  float ax = fabsf(x);
  float e = __expf(-2.f * ax);
  float r = (1.f - e) * __builtin_amdgcn_rcpf(1.f + e);
  return copysignf(r, x);
}

// LLC load (bypass L1+L2) — R8/R13-proven; sentinel re-reads never see stale L2.
__device__ __forceinline__ s8 ld128_llc(const unsigned short* p) {
  s8 v;
  asm volatile("global_load_dwordx4 %0, %1, off sc0 sc1" : "=&v"(v) : "v"(p) : "memory");
  return v;
}
#define VMCNT0 asm volatile("s_waitcnt vmcnt(0)" ::: "memory")
#define SBAR __builtin_amdgcn_sched_barrier(0)

__device__ __forceinline__ bool chk(s8 v) {  // both 8B halves non-sentinel
  return ((unsigned short)v[0] != (unsigned short)SENT) &
         ((unsigned short)v[4] != (unsigned short)SENT);
}

struct PT {
  const float* x;
  const float* Whh[3]; const float* Wih[3];
  const float* bih[3]; const float* bhh[3];
  const float* fcw;
  float* outbuf;
  unsigned short* y[3];
  unsigned* fl;    // [(L*32+s)*4+w]*16 per-producer flags (t+1), fire-and-forget
  unsigned* fcfl;  // [(s*4+w)]*16 layer-2 drained flags (every 8th step)
};

__global__ void zero_sync(unsigned* f) {
  int i = blockIdx.x * 256 + threadIdx.x;
  if (i < 8192) f[i] = 0;
}

// sentinel pre-fill of all y buffers (agent scope -> LLC)
__global__ void fill_y(u64* p) {
  const u64 pat = 0x7F807F807F807F80ull;
  size_t g = (size_t)blockIdx.x * 256 + threadIdx.x;
#pragma unroll
  for (int i = 0; i < 16; ++i)
    __hip_atomic_store(p + g + (size_t)i * 393216, pat, __ATOMIC_RELAXED,
                       __HIP_MEMORY_SCOPE_AGENT);
}

__global__ void bias_init_kernel(const float* __restrict__ fcb, float* __restrict__ out) {
  int i = blockIdx.x * 256 + threadIdx.x;
  if (i < Bb * Cc) out[i] = fcb[i % Cc];
}

// grid 256, 1 block/CU. bid<96: LSTM (L=bid>>5, s=bid&31, 16 dims/slice, per-wave
// batch chains). bid>=96: FC (160 blocks, tiles gated on fcfl).
// R13 protocol (flags as hints, sentinel verify as truth, fire-and-forget
// producers) with ONE change: payload loads are ISSUED BEFORE the flag poll so
// the LLC flight overlaps the detect. Invariant: at most one deferred-wait asm
// load array (64 VGPR) in flight at any time (R14's NaN was two at once).
__launch_bounds__(256, 1)
__global__ void mega_kernel(PT p) {
  const int bid = blockIdx.x;
  const int tid = threadIdx.x;
  const int lane = tid & 63;
  const int w = tid >> 6;
  const int q = lane >> 4;
  const int c = lane & 15;
  const int b = 16 * w + c;

  __shared__ unsigned short Whl[64 * 512];  // 64 KB swizzled (recurrent)
  __shared__ unsigned short Wil[64 * 512];  // 64 KB (input; L0 uses 64x256)

  if (bid < 96) {
    const int L = bid >> 5;
    const int s = bid & 31;
    const int n0 = s * 16;

    const int Kin = (L == 0) ? Ii : Hh;
    {  // stage: LDS row r=tt*16+rho <- gate-row (rho&3)*H + n0 + 4*(rho>>2) + tt
      const float* src = p.Whh[L];
      for (int idx = tid; idx < 64 * 64; idx += 256) {
        int r = idx >> 6, kk = (idx & 63) << 3;
        int rho = r & 15, tt = r >> 4;
        int j = (rho & 3) * Hh + n0 + 4 * (rho >> 2) + tt;
        const float* sr = src + (size_t)j * Hh + kk;
        s8 tv;
#pragma unroll
        for (int e = 0; e < 8; ++e) tv[e] = (short)f2bf(sr[e]);
        int byt = ((r * 512 + kk) * 2) ^ ((r & 7) << 4);
        *(s8*)((char*)Whl + byt) = tv;
      }
      const float* si = p.Wih[L];
      const int kd8 = Kin >> 3;
      for (int idx = tid; idx < 64 * kd8; idx += 256) {
        int r = idx / kd8, kk = (idx - r * kd8) << 3;
        int rho = r & 15, tt = r >> 4;
        int j = (rho & 3) * Hh + n0 + 4 * (rho >> 2) + tt;
        const float* sr = si + (size_t)j * Kin + kk;
        s8 tv;
#pragma unroll
        for (int e = 0; e < 8; ++e) tv[e] = (short)f2bf(sr[e]);
        int byt = ((r * Kin + kk) * 2) ^ ((r & 7) << 4);
        *(s8*)((char*)Wil + byt) = tv;
      }
    }

    f4 bias[4];
#pragma unroll
    for (int tt = 0; tt < 4; ++tt)
#pragma unroll
      for (int g = 0; g < 4; ++g) {
        int bi = g * Hh + n0 + 4 * q + tt;  // lane (q,c) tile tt -> dim n0+4q+tt
        bias[tt][g] = p.bih[L][bi] + p.bhh[L][bi];
      }
    float cst[4] = {0.f, 0.f, 0.f, 0.f};
    __syncthreads();

    const int aswz = (c & 7) << 4;
    unsigned short* yl = p.y[L];
    const unsigned short* ylow = (L > 0) ? p.y[L - 1] : (const unsigned short*)0;
    unsigned* flin = (L > 0) ? p.fl + ((L - 1) * 32) * 4 * 16 : (unsigned*)0;
    unsigned* flown = p.fl + (L * 32) * 4 * 16;
    unsigned* myfl = p.fl + ((L * 32 + s) * 4 + w) * 16;

    for (int t = 0; t < Tt; ++t) {
      f4 acc[4];
#pragma unroll
      for (int tt = 0; tt < 4; ++tt) acc[tt] = bias[tt];

      // ---- input acquisition + GEMM ----
      if (L == 0) {
        const float* xr = p.x + ((size_t)b * Tt + t) * Ii + 8 * q;
#pragma unroll
        for (int kc = 0; kc < 8; ++kc) {
          f4 xa = *(const f4*)(xr + kc * 32);
          f4 xc = *(const f4*)(xr + kc * 32 + 4);
          s8 xb;
#pragma unroll
          for (int e = 0; e < 4; ++e) { xb[e] = (short)f2bf(xa[e]); xb[e + 4] = (short)f2bf(xc[e]); }
#pragma unroll
          for (int tt = 0; tt < 4; ++tt) {
            int byt = (((tt * 16 + c) * 256 + kc * 32 + 8 * q) * 2) ^ aswz;
            s8 wa = *(const s8*)((const char*)Wil + byt);
            acc[tt] = __builtin_amdgcn_mfma_f32_16x16x32_bf16(wa, xb, acc[tt], 0, 0, 0);
          }
        }
      } else {
        // issue payload loads FIRST; poll flags while the 16KB flight is in the air
        const unsigned short* yr = ylow + ((size_t)b * Tt + t) * Hh + 8 * q;
        s8 yb[16];
#pragma unroll
        for (int kc = 0; kc < 16; ++kc) yb[kc] = ld128_llc(yr + kc * 32);
        while (!__all(lane < 32
                          ? __hip_atomic_load(flin + (lane * 4 + w) * 16, __ATOMIC_RELAXED,
                                              __HIP_MEMORY_SCOPE_AGENT) >= (unsigned)(t + 1)
                          : true))
          __builtin_amdgcn_s_sleep(1);
        asm volatile("" ::: "memory");
        VMCNT0; SBAR;
        while (1) {  // sentinel verify + selective re-read (early reads may be stale)
          unsigned bad = 0;
#pragma unroll
          for (int kc = 0; kc < 16; ++kc)
            if (!chk(yb[kc])) bad |= (1u << kc);
          if (__all(bad == 0)) break;
          __builtin_amdgcn_s_sleep(1);
#pragma unroll
          for (int kc = 0; kc < 16; ++kc)
            if (bad & (1u << kc)) yb[kc] = ld128_llc(yr + kc * 32);
          VMCNT0; SBAR;
        }
#pragma unroll
        for (int tt = 0; tt < 4; ++tt)
#pragma unroll
          for (int kc = 0; kc < 16; ++kc) {
            int byt = (((tt * 16 + c) * 512 + kc * 32 + 8 * q) * 2) ^ aswz;
            s8 wa = *(const s8*)((const char*)Wil + byt);
            acc[tt] = __builtin_amdgcn_mfma_f32_16x16x32_bf16(wa, yb[kc], acc[tt], 0, 0, 0);
          }
      }

      // ---- h[t-1]: issue loads, poll flags under the flight, verify, GEMM ----
      if (t > 0) {
        const unsigned short* hr = yl + ((size_t)b * Tt + (t - 1)) * Hh + 8 * q;
        s8 hb[16];
#pragma unroll
        for (int kc = 0; kc < 16; ++kc) hb[kc] = ld128_llc(hr + kc * 32);
        while (!__all(lane < 32
                          ? __hip_atomic_load(flown + (lane * 4 + w) * 16, __ATOMIC_RELAXED,
                                              __HIP_MEMORY_SCOPE_AGENT) >= (unsigned)t
                          : true))
          __builtin_amdgcn_s_sleep(1);
        asm volatile("" ::: "memory");
        VMCNT0; SBAR;
        while (1) {
          unsigned bad = 0;
#pragma unroll
          for (int kc = 0; kc < 16; ++kc)
            if (!chk(hb[kc])) bad |= (1u << kc);
          if (__all(bad == 0)) break;
          __builtin_amdgcn_s_sleep(1);
#pragma unroll
          for (int kc = 0; kc < 16; ++kc)
            if (bad & (1u << kc)) hb[kc] = ld128_llc(hr + kc * 32);
          VMCNT0; SBAR;
        }
#pragma unroll
        for (int tt = 0; tt < 4; ++tt)
#pragma unroll
          for (int kc = 0; kc < 16; ++kc) {
            int byt = (((tt * 16 + c) * 512 + kc * 32 + 8 * q) * 2) ^ aswz;
            s8 wa = *(const s8*)((const char*)Whl + byt);
            acc[tt] = __builtin_amdgcn_mfma_f32_16x16x32_bf16(wa, hb[kc], acc[tt], 0, 0, 0);
          }
      }

      // ---- pointwise: lane (q,c) dims n0+4q+tt, gates {i,f,g,o}=acc[tt][0..3] ----
      unsigned short hu[4];
#pragma unroll
      for (int tt = 0; tt < 4; ++tt) {
        float ii = sigf(acc[tt][0]), ff = sigf(acc[tt][1]);
        float gg = tanhs(acc[tt][2]), oo = sigf(acc[tt][3]);
        cst[tt] = ff * cst[tt] + ii * gg;
        hu[tt] = f2bf(oo * tanhs(cst[tt]));
      }
      u64 hv = (u64)hu[0] | ((u64)hu[1] << 16) | ((u64)hu[2] << 32) | ((u64)hu[3] << 48);
      u64* dst = (u64*)(yl + ((size_t)b * Tt + t) * Hh + n0 + 4 * q);
      // fire-and-forget: h store + flag, NO drain (consumers verify sentinels)
      __hip_atomic_store(dst, hv, __ATOMIC_RELAXED, __HIP_MEMORY_SCOPE_AGENT);
      if (lane == 0)
        __hip_atomic_store(myfl, (unsigned)(t + 1), __ATOMIC_RELAXED, __HIP_MEMORY_SCOPE_AGENT);
      // layer-2 only: amortized drained release for FC (sound gate, every 8 steps)
      if (L == 2 && (t & 7) == 7) {
        VMCNT0;
        if (lane == 0)
          __hip_atomic_store(p.fcfl + (s * 4 + w) * 16, (unsigned)(t + 1), __ATOMIC_RELAXED,
                             __HIP_MEMORY_SCOPE_AGENT);
      }
    }
  } else {
    // ======================= FC role =======================
    const int fcid = bid - 96;
    const int KT = Tt * Hh;
    const unsigned short* y2 = p.y[2];
    for (int ti = fcid; ti < 1024; ti += 160) {
      const int kch = ti >> 5, ct = ti & 31;
      const unsigned tneed1 = (unsigned)(kch * 8 + 8);  // fcfl value releasing this k-chunk
      bool ok;
      do {
        unsigned v = 0xFFFFFFFFu;
        if (lane < 32) {
          unsigned mn = 0xFFFFFFFFu;
#pragma unroll
          for (int ww = 0; ww < 4; ++ww) {
            unsigned vv = __hip_atomic_load(p.fcfl + (lane * 4 + ww) * 16, __ATOMIC_RELAXED,
                                            __HIP_MEMORY_SCOPE_AGENT);
            mn = mn < vv ? mn : vv;
          }
          v = mn;
        }
        ok = __all(v >= tneed1);
        if (!ok) __builtin_amdgcn_s_sleep(16);
      } while (!ok);
      asm volatile("" ::: "memory");

      const int kbase = kch * 4096 + q * 8;
      const int c0 = ct * 32 + c;
      const int c1 = c0 + 16;
      const bool v0 = (c0 < Cc), v1 = (c1 < Cc);
      const float* w0 = p.fcw + (size_t)c0 * KT;
      const float* w1 = p.fcw + (size_t)c1 * KT;
      const unsigned short* yr = y2 + (size_t)b * KT;
      f4 a0 = {0.f, 0.f, 0.f, 0.f}, a1 = {0.f, 0.f, 0.f, 0.f};
      for (int kk = 0; kk < 4096; kk += 32) {
        const int k = kbase + kk;
        s8 bf = *(const s8*)(yr + k);
        s8 wa0 = {0, 0, 0, 0, 0, 0, 0, 0}, wa1 = {0, 0, 0, 0, 0, 0, 0, 0};
        if (v0) {
#pragma unroll
          for (int qq = 0; qq < 8; ++qq) wa0[qq] = (short)f2bf(w0[k + qq]);
        }
        if (v1) {
#pragma unroll
          for (int qq = 0; qq < 8; ++qq) wa1[qq] = (short)f2bf(w1[k + qq]);
        }
        a0 = __builtin_amdgcn_mfma_f32_16x16x32_bf16(wa0, bf, a0, 0, 0, 0);
        a1 = __builtin_amdgcn_mfma_f32_16x16x32_bf16(wa1, bf, a1, 0, 0, 0);
      }
      const int rr = q * 4;
#pragma unroll
      for (int qq = 0; qq < 4; ++qq) {
        int ca = ct * 32 + rr + qq;
        if (ca < Cc) atomicAdd(p.outbuf + (size_t)b * Cc + ca, a0[qq]);
        int cb2 = ca + 16;
        if (cb2 < Cc) atomicAdd(p.outbuf + (size_t)b * Cc + cb2, a1[qq]);
      }
    }
  }
}

extern "C" void kernel_launch(void* const* d_in, const int* in_sizes, int n_in,
                              void* d_out, int out_size, void* d_ws, size_t ws_size,
                              hipStream_t stream) {
  PT p;
  p.x = (const float*)d_in[0];
  p.Wih[0] = (const float*)d_in[1];  p.Whh[0] = (const float*)d_in[2];
  p.bih[0] = (const float*)d_in[3];  p.bhh[0] = (const float*)d_in[4];
  p.Wih[1] = (const float*)d_in[5];  p.Whh[1] = (const float*)d_in[6];
  p.bih[1] = (const float*)d_in[7];  p.bhh[1] = (const float*)d_in[8];
  p.Wih[2] = (const float*)d_in[9];  p.Whh[2] = (const float*)d_in[10];
  p.bih[2] = (const float*)d_in[11]; p.bhh[2] = (const float*)d_in[12];
  p.fcw = (const float*)d_in[13];
  const float* fcb = (const float*)d_in[14];
  p.outbuf = (float*)d_out;

  char* ws = (char*)d_ws;
  p.fl = (unsigned*)ws;                 // 24 KB spread flags
  p.fcfl = p.fl + 6144;                 // 8 KB fc gates
  const size_t ysz = (size_t)Bb * Tt * Hh;
  unsigned short* y0 = (unsigned short*)(ws + 65536);
  p.y[0] = y0;
  p.y[1] = y0 + ysz;
  p.y[2] = y0 + 2 * ysz;

  zero_sync<<<32, 256, 0, stream>>>(p.fl);
  fill_y<<<1536, 256, 0, stream>>>((u64*)y0);  // 3*ysz*2 B = 6291456 u64 exactly
  bias_init_kernel<<<250, 256, 0, stream>>>(fcb, (float*)d_out);
  mega_kernel<<<256, 256, 0, stream>>>(p);
}